// Round 5
// baseline (459.100 us; speedup 1.0000x reference)
//
#include <hip/hip_runtime.h>
#include <hip/hip_bf16.h>
#include <hip/hip_fp16.h>

#define NP 8192
#define DF 256
#define PH1 4          // phase-1 Boruvka rounds (nc <= NP/2^PH1 = 512 guaranteed)
#define PH2 9          // phase-2 rounds on contracted matrix (512 -> 1)
#define NC 512         // max components at contract time
#define CAND_K 48
#define NBINS 2048
#define ALLR 13        // degraded path round count

typedef unsigned long long u64;
typedef unsigned int u32;
typedef unsigned short u16;
using bf16x8 = __attribute__((ext_vector_type(8))) short;
using f32x4  = __attribute__((ext_vector_type(4))) float;
using u16x8  = __attribute__((ext_vector_type(8))) u16;

__device__ __forceinline__ u16 f2bf(float f) {
  __hip_bfloat16 h = __float2bfloat16(f);
  return __builtin_bit_cast(u16, h);
}
__device__ __forceinline__ u16 f2h_bits(float f) {
  _Float16 h = (_Float16)f;
  return __builtin_bit_cast(u16, h);
}
__device__ __forceinline__ u64 mkkey(u32 vbits, int i, int j) {
  int lo = i < j ? i : j;
  int hi = i ^ j ^ lo;
  return ((u64)vbits << 26) | ((u64)lo << 13) | (u64)hi;
}

// ---------- init ----------

__global__ void init_kernel(int* comp, u64* compmin, int* edgeCnt, int* nComps, int* fbCnt) {
  int i = blockIdx.x * 256 + threadIdx.x;
  if (i < NP) { comp[i] = i; compmin[i] = ~0ull; }
  if (blockIdx.x == 0 && threadIdx.x < 16) fbCnt[threadIdx.x] = 0;
  if (i == 0) { *edgeCnt = 0; *nComps = NP; }
}

// ---------- row squared norms (fp32 exact) ----------

__global__ __launch_bounds__(64) void sq_kernel(const float* __restrict__ X, float* __restrict__ sq) {
  int i = blockIdx.x;
  float4 v = ((const float4*)(X + (size_t)i * DF))[threadIdx.x];
  float s = v.x * v.x + v.y * v.y + v.z * v.z + v.w * v.w;
#pragma unroll
  for (int off = 32; off >= 1; off >>= 1) s += __shfl_down(s, off);
  if (threadIdx.x == 0) sq[i] = s;
}

// ---------- fp32 -> bf16 conversion of X ----------

__global__ __launch_bounds__(256) void cvt_kernel(const float* __restrict__ X, u16* __restrict__ Xb) {
  int idx = (blockIdx.x * 256 + threadIdx.x) * 8;
  float4 a = ((const float4*)(X + idx))[0];
  float4 b = ((const float4*)(X + idx))[1];
  u16x8 o;
  o[0] = f2bf(a.x); o[1] = f2bf(a.y); o[2] = f2bf(a.z); o[3] = f2bf(a.w);
  o[4] = f2bf(b.x); o[5] = f2bf(b.y); o[6] = f2bf(b.z); o[7] = f2bf(b.w);
  *(u16x8*)(Xb + idx) = o;
}

// ---------- d2 build: bf16 MFMA 128x128 tile, LDS epilogue for coalesced stores ----------

template <bool PRE>
__global__ __launch_bounds__(256) void build_dist_kernel(
    const float* __restrict__ X, const u16* __restrict__ Xb,
    const float* __restrict__ sq, _Float16* __restrict__ d2) {
  __shared__ __align__(16) u16 smem[128 * 144];
  u16* At = smem;
  u16* Bt = smem + 128 * 40;
  const int t = threadIdx.x;
  const int m0 = blockIdx.y * 128, n0 = blockIdx.x * 128;
  const int wid = t >> 6, lane = t & 63;
  const int wm = wid >> 1, wn = wid & 1;
  const int lrow = lane & 15, lk = lane >> 4;
  f32x4 acc[4][4] = {};

  const int srow = t >> 1, shalf = t & 1;
  for (int k0 = 0; k0 < DF; k0 += 32) {
    u16x8 av0, av1, bv0, bv1;
    if (PRE) {
      const u16* pa = Xb + (size_t)(m0 + srow) * DF + k0 + shalf * 16;
      av0 = *(const u16x8*)pa; av1 = *(const u16x8*)(pa + 8);
      const u16* pb = Xb + (size_t)(n0 + srow) * DF + k0 + shalf * 16;
      bv0 = *(const u16x8*)pb; bv1 = *(const u16x8*)(pb + 8);
    } else {
      const float4* pa = (const float4*)(X + (size_t)(m0 + srow) * DF + k0 + shalf * 16);
      float4 a0 = pa[0], a1 = pa[1], a2 = pa[2], a3 = pa[3];
      av0[0]=f2bf(a0.x); av0[1]=f2bf(a0.y); av0[2]=f2bf(a0.z); av0[3]=f2bf(a0.w);
      av0[4]=f2bf(a1.x); av0[5]=f2bf(a1.y); av0[6]=f2bf(a1.z); av0[7]=f2bf(a1.w);
      av1[0]=f2bf(a2.x); av1[1]=f2bf(a2.y); av1[2]=f2bf(a2.z); av1[3]=f2bf(a2.w);
      av1[4]=f2bf(a3.x); av1[5]=f2bf(a3.y); av1[6]=f2bf(a3.z); av1[7]=f2bf(a3.w);
      const float4* pb = (const float4*)(X + (size_t)(n0 + srow) * DF + k0 + shalf * 16);
      float4 b0 = pb[0], b1 = pb[1], b2 = pb[2], b3 = pb[3];
      bv0[0]=f2bf(b0.x); bv0[1]=f2bf(b0.y); bv0[2]=f2bf(b0.z); bv0[3]=f2bf(b0.w);
      bv0[4]=f2bf(b1.x); bv0[5]=f2bf(b1.y); bv0[6]=f2bf(b1.z); bv0[7]=f2bf(b1.w);
      bv1[0]=f2bf(b2.x); bv1[1]=f2bf(b2.y); bv1[2]=f2bf(b2.z); bv1[3]=f2bf(b2.w);
      bv1[4]=f2bf(b3.x); bv1[5]=f2bf(b3.y); bv1[6]=f2bf(b3.z); bv1[7]=f2bf(b3.w);
    }
    __syncthreads();
    *(u16x8*)&At[srow * 40 + shalf * 16] = av0;
    *(u16x8*)&At[srow * 40 + shalf * 16 + 8] = av1;
    *(u16x8*)&Bt[srow * 40 + shalf * 16] = bv0;
    *(u16x8*)&Bt[srow * 40 + shalf * 16 + 8] = bv1;
    __syncthreads();
    bf16x8 af[4], bfr[4];
#pragma unroll
    for (int fm = 0; fm < 4; ++fm)
      af[fm] = *(const bf16x8*)&At[(wm * 64 + fm * 16 + lrow) * 40 + lk * 8];
#pragma unroll
    for (int fn = 0; fn < 4; ++fn)
      bfr[fn] = *(const bf16x8*)&Bt[(wn * 64 + fn * 16 + lrow) * 40 + lk * 8];
#pragma unroll
    for (int fm = 0; fm < 4; ++fm)
#pragma unroll
      for (int fn = 0; fn < 4; ++fn)
        acc[fm][fn] = __builtin_amdgcn_mfma_f32_16x16x32_bf16(af[fm], bfr[fn], acc[fm][fn], 0, 0, 0);
  }
  __syncthreads();

  float sqj[4];
#pragma unroll
  for (int fn = 0; fn < 4; ++fn) sqj[fn] = sq[n0 + wn * 64 + fn * 16 + lrow];
#pragma unroll
  for (int fm = 0; fm < 4; ++fm) {
#pragma unroll
    for (int r = 0; r < 4; ++r) {
      int row = wm * 64 + fm * 16 + lk * 4 + r;
      int i = m0 + row;
      float si = sq[i];
#pragma unroll
      for (int fn = 0; fn < 4; ++fn) {
        int col = wn * 64 + fn * 16 + lrow;
        float dd = si + sqj[fn] - 2.0f * acc[fm][fn][r];
        dd = fmaxf(dd, 0.0f);
        if (i == n0 + col) dd = INFINITY;
        smem[row * 144 + col] = f2h_bits(dd);
      }
    }
  }
  __syncthreads();
#pragma unroll
  for (int k = 0; k < 8; ++k) {
    int flat = k * 256 + t;
    int row = flat >> 4, cb = (flat & 15) * 8;
    *(u16x8*)&d2[(size_t)(m0 + row) * NP + n0 + cb] = *(const u16x8*)&smem[row * 144 + cb];
  }
}

// ---------- per-row exact candidate extraction (histogram select, prefix property) ----------

__global__ __launch_bounds__(256) void topk_kernel(const _Float16* __restrict__ d2,
                                                   u64* __restrict__ candT,
                                                   u32* __restrict__ candCnt) {
  __shared__ u16 rowbuf[NP];
  __shared__ u32 hist[NBINS];
  __shared__ u32 scanw[4];
  __shared__ int swred[4];
  __shared__ int sB;
  __shared__ u32 sCnt;
  const int i = blockIdx.x;
  const int t = threadIdx.x;
  const u16* row = (const u16*)(d2 + (size_t)i * NP);
  for (int b = t; b < NBINS; b += 256) hist[b] = 0;
  if (t == 0) sCnt = 0;
  __syncthreads();
  for (int base = t * 8; base < NP; base += 2048) {
    u16x8 v = *(const u16x8*)(row + base);
    *(u16x8*)&rowbuf[base] = v;
#pragma unroll
    for (int q = 0; q < 8; ++q) atomicAdd(&hist[v[q] >> 5], 1u);
  }
  __syncthreads();
  u32 loc[8]; u32 s = 0;
#pragma unroll
  for (int q = 0; q < 8; ++q) { loc[q] = hist[t * 8 + q]; s += loc[q]; }
  u32 pre = s;
  for (int off = 1; off < 64; off <<= 1) {
    u32 o = __shfl_up(pre, off);
    if ((t & 63) >= off) pre += o;
  }
  if ((t & 63) == 63) scanw[t >> 6] = pre;
  __syncthreads();
  u32 wbase = 0;
  for (int w = 0; w < (t >> 6); ++w) wbase += scanw[w];
  u32 c = wbase + pre - s;
  int lb = -1;
#pragma unroll
  for (int q = 0; q < 8; ++q) {
    c += loc[q];
    if (c >= 1 && c <= CAND_K) lb = t * 8 + q;
  }
#pragma unroll
  for (int off = 32; off >= 1; off >>= 1) {
    int o = __shfl_down(lb, off);
    lb = lb > o ? lb : o;
  }
  if ((t & 63) == 0) swred[t >> 6] = lb;
  __syncthreads();
  if (t == 0) {
    int m = swred[0];
#pragma unroll
    for (int w = 1; w < 4; ++w) m = m > swred[w] ? m : swred[w];
    sB = m;
  }
  __syncthreads();
  const int B = sB;
  if (B >= 0) {
    for (int base = t * 8; base < NP; base += 2048) {
#pragma unroll
      for (int q = 0; q < 8; ++q) {
        u16 v = rowbuf[base + q];
        if ((int)(v >> 5) <= B) {
          u32 pos = atomicAdd(&sCnt, 1u);
          if (pos < CAND_K) candT[(size_t)pos * NP + i] = mkkey(v, i, base + q);
        }
      }
    }
  }
  __syncthreads();
  if (t == 0) {
    u32 n = sCnt;
    candCnt[i] = (n == 0 || n > CAND_K) ? 0x80000000u : n;
  }
}

// ---------- phase-1 per-round: cand scan; exhausted rows -> fallback list ----------

__global__ __launch_bounds__(256) void cand_min_kernel(
    const u64* __restrict__ candT, const u32* __restrict__ candCnt,
    const int* __restrict__ comp, u64* __restrict__ compmin,
    const int* __restrict__ nComps, int* __restrict__ fbList,
    int* __restrict__ fbCnt, int r) {
  if (*nComps == 1) return;
  const int i = blockIdx.x * 256 + threadIdx.x;
  const int ci = comp[i];
  u32 cc = candCnt[i];
  int n = (int)(cc & 0x7fffffffu);
  u64 best = ~0ull;
  for (int k = 0; k < n; ++k) {
    u64 key = candT[(size_t)k * NP + i];
    int lo = (int)((key >> 13) & 0x1FFF);
    int hi = (int)(key & 0x1FFF);
    int j = (lo == i) ? hi : lo;
    if (comp[j] != ci && key < best) best = key;
  }
  if (best != ~0ull && !(cc & 0x80000000u)) {
    atomicMin(&compmin[ci], best);
  } else {
    int p = atomicAdd(&fbCnt[r], 1);
    fbList[p] = i;
  }
}

// ---------- phase-1 fallback: parallel block-per-row full scans over list ----------

__global__ __launch_bounds__(256) void fb_kernel(
    const _Float16* __restrict__ d2, const int* __restrict__ comp,
    u64* __restrict__ compmin, const int* __restrict__ fbList,
    const int* __restrict__ fbCnt, int r, const int* __restrict__ nComps) {
  if (*nComps == 1) return;
  __shared__ u64 sred[4];
  const int t = threadIdx.x;
  const int n = fbCnt[r];
  for (int idx = blockIdx.x; idx < n; idx += gridDim.x) {
    const int i = fbList[idx];
    const int ci = comp[i];
    const u16* row = (const u16*)(d2 + (size_t)i * NP);
    u64 best = ~0ull;
    for (int base = t * 8; base < NP; base += 2048) {
      u16x8 v = *(const u16x8*)(row + base);
      int4 c0 = *(const int4*)(comp + base);
      int4 c1 = *(const int4*)(comp + base + 4);
      int cs[8] = {c0.x, c0.y, c0.z, c0.w, c1.x, c1.y, c1.z, c1.w};
#pragma unroll
      for (int q = 0; q < 8; ++q) {
        if (cs[q] != ci) {
          u64 k = mkkey(v[q], i, base + q);
          best = k < best ? k : best;
        }
      }
    }
#pragma unroll
    for (int off = 32; off >= 1; off >>= 1) {
      u64 o = __shfl_down(best, off);
      best = best < o ? best : o;
    }
    if ((t & 63) == 0) sred[t >> 6] = best;
    __syncthreads();
    if (t == 0) {
      best = sred[0];
#pragma unroll
      for (int w = 1; w < 4; ++w) best = best < sred[w] ? best : sred[w];
      if (best != ~0ull) atomicMin(&compmin[ci], best);
    }
    __syncthreads();
  }
}

// ---------- phase-1 select (structural 2-cycle dedupe), exact fp32 weights ----------

__global__ void select_kernel(const float* __restrict__ X, const float* __restrict__ sq,
                              const int* __restrict__ comp, const u64* __restrict__ compmin,
                              int* __restrict__ parent, float* __restrict__ edgeW,
                              int* __restrict__ edgeCnt, const int* __restrict__ nComps) {
  int c = blockIdx.x * blockDim.x + threadIdx.x;
  if (c >= NP) return;
  if (*nComps == 1) { parent[c] = c; return; }
  u64 m = compmin[c];
  if (m == ~0ull) { parent[c] = c; return; }
  int a = (int)((m >> 13) & 0x1FFF);
  int b = (int)(m & 0x1FFF);
  int j = (comp[a] == c) ? b : a;
  int d = comp[j];
  bool mutual = false;
  u64 md = compmin[d];
  if (md != ~0ull) {
    int a2 = (int)((md >> 13) & 0x1FFF);
    int b2 = (int)(md & 0x1FFF);
    int j2 = (comp[a2] == d) ? b2 : a2;
    mutual = (comp[j2] == c);
  }
  if (mutual && c > d) { parent[c] = d; return; }
  parent[c] = mutual ? c : d;
  const float4* pa = (const float4*)(X + (size_t)a * DF);
  const float4* pb = (const float4*)(X + (size_t)b * DF);
  float dot = 0.f;
#pragma unroll 8
  for (int k = 0; k < DF / 4; ++k) {
    float4 va = pa[k], vb = pb[k];
    dot += va.x * vb.x + va.y * vb.y + va.z * vb.z + va.w * vb.w;
  }
  float dd = sq[a] + sq[b] - 2.f * dot;
  float w = sqrtf(fmaxf(dd, 0.f) + 1e-12f);
  int idx = atomicAdd(edgeCnt, 1);
  if (idx < NP) edgeW[idx] = w;
}

// ---------- phase-1 pointer-jump + relabel + count; DENSE also builds contraction maps ----------

template <bool DENSE>
__global__ __launch_bounds__(1024) void jump_relabel_kernel(
    const int* __restrict__ parent, int* __restrict__ comp,
    u64* __restrict__ compmin, int* __restrict__ nComps,
    u16* __restrict__ dcomp, int* __restrict__ comp2, int* __restrict__ parent2,
    u64* __restrict__ compmin2, int* __restrict__ ncDense) {
  if (*nComps == 1) return;
  __shared__ int sp[NP];
  __shared__ u16 did[NP];
  __shared__ int swsum[16];
  __shared__ int scnt;
  __shared__ int sch;
  const int t = threadIdx.x;
  const int lane = t & 63, wv = t >> 6;
  for (int c = t; c < NP; c += 1024) { sp[c] = parent[c]; did[c] = 0; }
  if (t == 0) { scnt = 0; sch = 0; }
  __syncthreads();
  for (int it = 0; it < 13; ++it) {
    int ch = 0;
    for (int c = t; c < NP; c += 1024) {
      int p = sp[c];
      int pp = sp[p];
      if (p != pp) { sp[c] = pp; ch = 1; }
    }
    if (ch) sch = 1;
    __syncthreads();
    if (!sch) break;
    __syncthreads();
    if (t == 0) sch = 0;
    __syncthreads();
  }
  for (int i = t; i < NP; i += 1024) {
    int nc = sp[comp[i]];
    comp[i] = nc;
    did[nc] = 1;
  }
  __syncthreads();
  if constexpr (!DENSE) {
    int part = 0;
    for (int c = t; c < NP; c += 1024) part += did[c];
#pragma unroll
    for (int off = 32; off >= 1; off >>= 1) part += __shfl_down(part, off);
    if (lane == 0) atomicAdd(&scnt, part);
    for (int c = t; c < NP; c += 1024) compmin[c] = ~0ull;
    __syncthreads();
    if (t == 0) *nComps = scnt;
  } else {
    // dense ids via block prefix sum over 8192 flags (8 per thread)
    int f[8]; int s = 0;
#pragma unroll
    for (int q = 0; q < 8; ++q) { f[q] = did[t * 8 + q]; s += f[q]; }
    int incl = s;
    for (int off = 1; off < 64; off <<= 1) {
      int o = __shfl_up(incl, off);
      if (lane >= off) incl += o;
    }
    if (lane == 63) swsum[wv] = incl;
    __syncthreads();
    int wbase = 0;
    for (int w = 0; w < wv; ++w) wbase += swsum[w];
    int e = wbase + incl - s;
#pragma unroll
    for (int q = 0; q < 8; ++q) {
      if (f[q]) { did[t * 8 + q] = (u16)e; ++e; }
    }
    __syncthreads();
    for (int i = t; i < NP; i += 1024) dcomp[i] = did[comp[i]];
    if (t < NC) { comp2[t] = t; parent2[t] = t; compmin2[t] = ~0ull; }
    if (t == 0) {
      int total = 0;
#pragma unroll
      for (int w = 0; w < 16; ++w) total += swsum[w];
      *nComps = total;
      *ncDense = total;
    }
  }
}

// ---------- M init (all-ones) ----------

__global__ __launch_bounds__(256) void minit_kernel(u64* __restrict__ M) {
  int idx = (blockIdx.x * 256 + threadIdx.x) * 4;
#pragma unroll
  for (int q = 0; q < 4; ++q) M[idx + q] = ~0ull;
}

// ---------- contract: full d2 pass -> M[NC][NC] exact min keys ----------
// Per-row LDS table keyed by dense comp; u32 entries (val16|j13) are order-
// equivalent to the u64 key within a fixed row i (proof: for equal val, the
// smaller j gives the smaller (lo,hi) pair when i is fixed).

__global__ __launch_bounds__(256) void contract_kernel(
    const _Float16* __restrict__ d2, const u16* __restrict__ dcomp,
    u64* __restrict__ M) {
  __shared__ u32 table[NC];
  const int i = blockIdx.x;
  const int t = threadIdx.x;
  for (int b = t; b < NC; b += 256) table[b] = ~0u;
  __syncthreads();
  const int ci = dcomp[i];
  const u16* row = (const u16*)(d2 + (size_t)i * NP);
  for (int base = t * 8; base < NP; base += 2048) {
    u16x8 v = *(const u16x8*)(row + base);
    u16x8 cj = *(const u16x8*)(dcomp + base);
#pragma unroll
    for (int q = 0; q < 8; ++q) {
      if (cj[q] != ci) {
        u32 k32 = ((u32)v[q] << 13) | (u32)(base + q);
        atomicMin(&table[cj[q]], k32);
      }
    }
  }
  __syncthreads();
  for (int b = t; b < NC; b += 256) {
    u32 k32 = table[b];
    if (k32 != ~0u) {
      u64 key = mkkey(k32 >> 13, i, (int)(k32 & 0x1FFF));
      u64* addr = &M[(size_t)ci * NC + b];
      if (key < *addr) atomicMin(addr, key);  // stale-read filter is safe: M only decreases
    }
  }
}

// ---------- phase-2: row min over M ----------

__global__ __launch_bounds__(64) void rmin2_kernel(const u64* __restrict__ M,
                                                   const int* __restrict__ comp2,
                                                   u64* __restrict__ compmin2,
                                                   const int* __restrict__ nComps) {
  if (*nComps == 1) return;
  const int a = blockIdx.x;
  const int t = threadIdx.x;
  const int ca = comp2[a];
  u64 best = ~0ull;
  for (int b = t; b < NC; b += 64) {
    u64 k = M[(size_t)a * NC + b];
    if (k != ~0ull && comp2[b] != ca && k < best) best = k;
  }
#pragma unroll
  for (int off = 32; off >= 1; off >>= 1) {
    u64 o = __shfl_down(best, off);
    best = best < o ? best : o;
  }
  if (t == 0 && best != ~0ull) atomicMin(&compmin2[ca], best);
}

// ---------- phase-2 select over dense comps ----------

__global__ void select2_kernel(const float* __restrict__ X, const float* __restrict__ sq,
                               const u16* __restrict__ dcomp, const int* __restrict__ comp2,
                               const u64* __restrict__ compmin2, int* __restrict__ parent2,
                               float* __restrict__ edgeW, int* __restrict__ edgeCnt,
                               const int* __restrict__ nComps) {
  int c = blockIdx.x * blockDim.x + threadIdx.x;
  if (c >= NC) return;
  if (*nComps == 1) { parent2[c] = c; return; }
  u64 m = compmin2[c];
  if (m == ~0ull) { parent2[c] = c; return; }
  int a = (int)((m >> 13) & 0x1FFF);
  int b = (int)(m & 0x1FFF);
  int j = (comp2[dcomp[a]] == c) ? b : a;
  int d = comp2[dcomp[j]];
  bool mutual = false;
  u64 md = compmin2[d];
  if (md != ~0ull) {
    int a2 = (int)((md >> 13) & 0x1FFF);
    int b2 = (int)(md & 0x1FFF);
    int j2 = (comp2[dcomp[a2]] == d) ? b2 : a2;
    mutual = (comp2[dcomp[j2]] == c);
  }
  if (mutual && c > d) { parent2[c] = d; return; }
  parent2[c] = mutual ? c : d;
  const float4* pa = (const float4*)(X + (size_t)a * DF);
  const float4* pb = (const float4*)(X + (size_t)b * DF);
  float dot = 0.f;
#pragma unroll 8
  for (int k = 0; k < DF / 4; ++k) {
    float4 va = pa[k], vb = pb[k];
    dot += va.x * vb.x + va.y * vb.y + va.z * vb.z + va.w * vb.w;
  }
  float dd = sq[a] + sq[b] - 2.f * dot;
  float w = sqrtf(fmaxf(dd, 0.f) + 1e-12f);
  int idx = atomicAdd(edgeCnt, 1);
  if (idx < NP) edgeW[idx] = w;
}

// ---------- phase-2 jump + relabel + count (single block over NC) ----------

__global__ __launch_bounds__(NC) void jump2_kernel(const int* __restrict__ parent2,
                                                   int* __restrict__ comp2,
                                                   u64* __restrict__ compmin2,
                                                   int* __restrict__ nComps,
                                                   const int* __restrict__ ncDense) {
  if (*nComps == 1) return;
  __shared__ int sp[NC];
  __shared__ u16 fl[NC];
  __shared__ int scnt;
  const int t = threadIdx.x;
  sp[t] = parent2[t];
  fl[t] = 0;
  if (t == 0) scnt = 0;
  __syncthreads();
#pragma unroll
  for (int it = 0; it < 9; ++it) {
    sp[t] = sp[sp[t]];
    __syncthreads();
  }
  int nd = *ncDense;
  int nc2 = sp[comp2[t]];
  comp2[t] = nc2;
  if (t < nd) fl[nc2] = 1;
  __syncthreads();
  int part = fl[t];
#pragma unroll
  for (int off = 32; off >= 1; off >>= 1) part += __shfl_down(part, off);
  if ((t & 63) == 0) atomicAdd(&scnt, part);
  compmin2[t] = ~0ull;
  __syncthreads();
  if (t == 0) *nComps = scnt;
}

// ---------- entropy over edge weights ----------

__global__ __launch_bounds__(1024) void entropy_kernel(const float* __restrict__ edgeW,
                                                       const int* __restrict__ edgeCnt,
                                                       float* __restrict__ out) {
  __shared__ float sred[16];
  __shared__ float stot;
  int ne = *edgeCnt;
  if (ne > NP) ne = NP;
  float s = 0.f;
  for (int k = threadIdx.x; k < ne; k += 1024) s += edgeW[k];
#pragma unroll
  for (int off = 32; off >= 1; off >>= 1) s += __shfl_down(s, off);
  int lane = threadIdx.x & 63, wv = threadIdx.x >> 6;
  if (lane == 0) sred[wv] = s;
  __syncthreads();
  if (threadIdx.x == 0) {
    float tt = 0.f;
#pragma unroll
    for (int w = 0; w < 16; ++w) tt += sred[w];
    stot = tt;
  }
  __syncthreads();
  float total = stot;
  float acc = 0.f;
  for (int k = threadIdx.x; k < ne; k += 1024) {
    float p = edgeW[k] / (total + 1e-12f);
    acc += p * logf(p + 1e-12f);
  }
#pragma unroll
  for (int off = 32; off >= 1; off >>= 1) acc += __shfl_down(acc, off);
  if (lane == 0) sred[wv] = acc;
  __syncthreads();
  if (threadIdx.x == 0) {
    float tt = 0.f;
#pragma unroll
    for (int w = 0; w < 16; ++w) tt += sred[w];
    out[0] = tt;  // loss = -entropy = sum p*log(p+eps); WEIGHT = 1
  }
}

// ---------- host-side driver ----------

extern "C" void kernel_launch(void* const* d_in, const int* in_sizes, int n_in,
                              void* d_out, int out_size, void* d_ws, size_t ws_size,
                              hipStream_t stream) {
  const float* X = (const float*)d_in[0];
  float* out = (float*)d_out;
  char* ws = (char*)d_ws;

  const size_t nn = (size_t)NP * NP;
  size_t off = (nn * 2 + 255) & ~(size_t)255;  // fp16 d2
  _Float16* d2 = (_Float16*)ws;
  float* sq = (float*)(ws + off);      off += (size_t)NP * 4;
  int* comp = (int*)(ws + off);        off += (size_t)NP * 4;
  u64* compmin = (u64*)(ws + off);     off += (size_t)NP * 8;
  int* parent = (int*)(ws + off);      off += (size_t)NP * 4;
  float* edgeW = (float*)(ws + off);   off += (size_t)NP * 4;
  u32* candCnt = (u32*)(ws + off);     off += (size_t)NP * 4;
  int* fbList = (int*)(ws + off);      off += (size_t)NP * 4;
  u16* dcomp = (u16*)(ws + off);       off += (size_t)NP * 2;
  int* comp2 = (int*)(ws + off);       off += (size_t)NC * 4;
  int* parent2 = (int*)(ws + off);     off += (size_t)NC * 4;
  u64* compmin2 = (u64*)(ws + off);    off += (size_t)NC * 8;
  int* edgeCnt = (int*)(ws + off);     off += 64;
  int* nComps = (int*)(ws + off);      off += 64;
  int* ncDense = (int*)(ws + off);     off += 64;
  int* fbCnt = (int*)(ws + off);       off += 64;
  off = (off + 255) & ~(size_t)255;
  // region R: Xb (4 MB, dead after build) | candT (3 MB, dead after phase 1) | M (2 MB)
  u16* Xb = (u16*)(ws + off);
  u64* candT = (u64*)(ws + off);
  u64* M = (u64*)(ws + off);
  const bool PRE = (ws_size >= off + (size_t)NP * DF * 2);
  const bool useM = (ws_size >= off + (size_t)NC * NC * 8);

  init_kernel<<<NP / 256, 256, 0, stream>>>(comp, compmin, edgeCnt, nComps, fbCnt);
  sq_kernel<<<NP, 64, 0, stream>>>(X, sq);
  if (PRE) {
    cvt_kernel<<<NP * DF / (256 * 8), 256, 0, stream>>>(X, Xb);
    build_dist_kernel<true><<<dim3(NP / 128, NP / 128), 256, 0, stream>>>(X, Xb, sq, d2);
  } else {
    build_dist_kernel<false><<<dim3(NP / 128, NP / 128), 256, 0, stream>>>(X, Xb, sq, d2);
  }
  topk_kernel<<<NP, 256, 0, stream>>>(d2, candT, candCnt);

  const int p1 = useM ? PH1 : ALLR;
  for (int r = 0; r < p1; ++r) {
    cand_min_kernel<<<NP / 256, 256, 0, stream>>>(candT, candCnt, comp, compmin, nComps,
                                                  fbList, fbCnt, r);
    fb_kernel<<<128, 256, 0, stream>>>(d2, comp, compmin, fbList, fbCnt, r, nComps);
    select_kernel<<<NP / 256, 256, 0, stream>>>(X, sq, comp, compmin, parent, edgeW,
                                                edgeCnt, nComps);
    if (useM && r == p1 - 1) {
      jump_relabel_kernel<true><<<1, 1024, 0, stream>>>(parent, comp, compmin, nComps,
                                                        dcomp, comp2, parent2, compmin2, ncDense);
    } else {
      jump_relabel_kernel<false><<<1, 1024, 0, stream>>>(parent, comp, compmin, nComps,
                                                         dcomp, comp2, parent2, compmin2, ncDense);
    }
  }

  if (useM) {
    minit_kernel<<<NC * NC / (256 * 4), 256, 0, stream>>>(M);
    contract_kernel<<<NP, 256, 0, stream>>>(d2, dcomp, M);
    for (int r = 0; r < PH2; ++r) {
      rmin2_kernel<<<NC, 64, 0, stream>>>(M, comp2, compmin2, nComps);
      select2_kernel<<<NC / 256, 256, 0, stream>>>(X, sq, dcomp, comp2, compmin2, parent2,
                                                   edgeW, edgeCnt, nComps);
      jump2_kernel<<<1, NC, 0, stream>>>(parent2, comp2, compmin2, nComps, ncDense);
    }
  }

  entropy_kernel<<<1, 1024, 0, stream>>>(edgeW, edgeCnt, out);
}

// Round 7
// 408.629 us; speedup vs baseline: 1.1235x; 1.1235x over previous
//
#include <hip/hip_runtime.h>
#include <hip/hip_bf16.h>
#include <hip/hip_fp16.h>

#define NP 8192
#define DF 256
#define PH1 4          // phase-1 Boruvka rounds (nc <= NP/2^PH1 = 512 guaranteed)
#define PH2 9          // phase-2 rounds on contracted matrix (512 -> 1)
#define NC 512         // max components at contract time
#define CAND_K 48
#define CAND_PAD 64
#define NBINS 2048
#define ALLR 13        // degraded path round count

typedef unsigned long long u64;
typedef unsigned int u32;
typedef unsigned short u16;
using bf16x8 = __attribute__((ext_vector_type(8))) short;
using f32x4  = __attribute__((ext_vector_type(4))) float;
using u16x8  = __attribute__((ext_vector_type(8))) u16;

__device__ __forceinline__ u16 f2bf(float f) {
  __hip_bfloat16 h = __float2bfloat16(f);
  return __builtin_bit_cast(u16, h);
}
__device__ __forceinline__ u16 f2h_bits(float f) {
  _Float16 h = (_Float16)f;
  return __builtin_bit_cast(u16, h);
}
__device__ __forceinline__ u64 mkkey(u32 vbits, int i, int j) {
  int lo = i < j ? i : j;
  int hi = i ^ j ^ lo;
  return ((u64)vbits << 26) | ((u64)lo << 13) | (u64)hi;
}

// ---------- init ----------

__global__ void init_kernel(int* comp, u64* compmin, int* edgeCnt, int* nComps, int* fbCnt) {
  int i = blockIdx.x * 256 + threadIdx.x;
  if (i < NP) { comp[i] = i; compmin[i] = ~0ull; }
  if (blockIdx.x == 0 && threadIdx.x < 16) fbCnt[threadIdx.x] = 0;
  if (i == 0) { *edgeCnt = 0; *nComps = NP; }
}

// ---------- row squared norms (fp32 exact) ----------

__global__ __launch_bounds__(64) void sq_kernel(const float* __restrict__ X, float* __restrict__ sq) {
  int i = blockIdx.x;
  float4 v = ((const float4*)(X + (size_t)i * DF))[threadIdx.x];
  float s = v.x * v.x + v.y * v.y + v.z * v.z + v.w * v.w;
#pragma unroll
  for (int off = 32; off >= 1; off >>= 1) s += __shfl_down(s, off);
  if (threadIdx.x == 0) sq[i] = s;
}

// ---------- fp32 -> bf16 conversion of X ----------

__global__ __launch_bounds__(256) void cvt_kernel(const float* __restrict__ X, u16* __restrict__ Xb) {
  int idx = (blockIdx.x * 256 + threadIdx.x) * 8;
  float4 a = ((const float4*)(X + idx))[0];
  float4 b = ((const float4*)(X + idx))[1];
  u16x8 o;
  o[0] = f2bf(a.x); o[1] = f2bf(a.y); o[2] = f2bf(a.z); o[3] = f2bf(a.w);
  o[4] = f2bf(b.x); o[5] = f2bf(b.y); o[6] = f2bf(b.z); o[7] = f2bf(b.w);
  *(u16x8*)(Xb + idx) = o;
}

// ---------- d2 build: bf16 MFMA 128x128 tile, LDS epilogue for coalesced stores ----------

template <bool PRE>
__global__ __launch_bounds__(256) void build_dist_kernel(
    const float* __restrict__ X, const u16* __restrict__ Xb,
    const float* __restrict__ sq, _Float16* __restrict__ d2) {
  __shared__ __align__(16) u16 smem[128 * 144];
  u16* At = smem;
  u16* Bt = smem + 128 * 40;
  const int t = threadIdx.x;
  const int m0 = blockIdx.y * 128, n0 = blockIdx.x * 128;
  const int wid = t >> 6, lane = t & 63;
  const int wm = wid >> 1, wn = wid & 1;
  const int lrow = lane & 15, lk = lane >> 4;
  f32x4 acc[4][4] = {};

  const int srow = t >> 1, shalf = t & 1;
  for (int k0 = 0; k0 < DF; k0 += 32) {
    u16x8 av0, av1, bv0, bv1;
    if (PRE) {
      const u16* pa = Xb + (size_t)(m0 + srow) * DF + k0 + shalf * 16;
      av0 = *(const u16x8*)pa; av1 = *(const u16x8*)(pa + 8);
      const u16* pb = Xb + (size_t)(n0 + srow) * DF + k0 + shalf * 16;
      bv0 = *(const u16x8*)pb; bv1 = *(const u16x8*)(pb + 8);
    } else {
      const float4* pa = (const float4*)(X + (size_t)(m0 + srow) * DF + k0 + shalf * 16);
      float4 a0 = pa[0], a1 = pa[1], a2 = pa[2], a3 = pa[3];
      av0[0]=f2bf(a0.x); av0[1]=f2bf(a0.y); av0[2]=f2bf(a0.z); av0[3]=f2bf(a0.w);
      av0[4]=f2bf(a1.x); av0[5]=f2bf(a1.y); av0[6]=f2bf(a1.z); av0[7]=f2bf(a1.w);
      av1[0]=f2bf(a2.x); av1[1]=f2bf(a2.y); av1[2]=f2bf(a2.z); av1[3]=f2bf(a2.w);
      av1[4]=f2bf(a3.x); av1[5]=f2bf(a3.y); av1[6]=f2bf(a3.z); av1[7]=f2bf(a3.w);
      const float4* pb = (const float4*)(X + (size_t)(n0 + srow) * DF + k0 + shalf * 16);
      float4 b0 = pb[0], b1 = pb[1], b2 = pb[2], b3 = pb[3];
      bv0[0]=f2bf(b0.x); bv0[1]=f2bf(b0.y); bv0[2]=f2bf(b0.z); bv0[3]=f2bf(b0.w);
      bv0[4]=f2bf(b1.x); bv0[5]=f2bf(b1.y); bv0[6]=f2bf(b1.z); bv0[7]=f2bf(b1.w);
      bv1[0]=f2bf(b2.x); bv1[1]=f2bf(b2.y); bv1[2]=f2bf(b2.z); bv1[3]=f2bf(b2.w);
      bv1[4]=f2bf(b3.x); bv1[5]=f2bf(b3.y); bv1[6]=f2bf(b3.z); bv1[7]=f2bf(b3.w);
    }
    __syncthreads();
    *(u16x8*)&At[srow * 40 + shalf * 16] = av0;
    *(u16x8*)&At[srow * 40 + shalf * 16 + 8] = av1;
    *(u16x8*)&Bt[srow * 40 + shalf * 16] = bv0;
    *(u16x8*)&Bt[srow * 40 + shalf * 16 + 8] = bv1;
    __syncthreads();
    bf16x8 af[4], bfr[4];
#pragma unroll
    for (int fm = 0; fm < 4; ++fm)
      af[fm] = *(const bf16x8*)&At[(wm * 64 + fm * 16 + lrow) * 40 + lk * 8];
#pragma unroll
    for (int fn = 0; fn < 4; ++fn)
      bfr[fn] = *(const bf16x8*)&Bt[(wn * 64 + fn * 16 + lrow) * 40 + lk * 8];
#pragma unroll
    for (int fm = 0; fm < 4; ++fm)
#pragma unroll
      for (int fn = 0; fn < 4; ++fn)
        acc[fm][fn] = __builtin_amdgcn_mfma_f32_16x16x32_bf16(af[fm], bfr[fn], acc[fm][fn], 0, 0, 0);
  }
  __syncthreads();

  float sqj[4];
#pragma unroll
  for (int fn = 0; fn < 4; ++fn) sqj[fn] = sq[n0 + wn * 64 + fn * 16 + lrow];
#pragma unroll
  for (int fm = 0; fm < 4; ++fm) {
#pragma unroll
    for (int r = 0; r < 4; ++r) {
      int row = wm * 64 + fm * 16 + lk * 4 + r;
      int i = m0 + row;
      float si = sq[i];
#pragma unroll
      for (int fn = 0; fn < 4; ++fn) {
        int col = wn * 64 + fn * 16 + lrow;
        float dd = si + sqj[fn] - 2.0f * acc[fm][fn][r];
        dd = fmaxf(dd, 0.0f);
        if (i == n0 + col) dd = INFINITY;
        smem[row * 144 + col] = f2h_bits(dd);
      }
    }
  }
  __syncthreads();
#pragma unroll
  for (int k = 0; k < 8; ++k) {
    int flat = k * 256 + t;
    int row = flat >> 4, cb = (flat & 15) * 8;
    *(u16x8*)&d2[(size_t)(m0 + row) * NP + n0 + cb] = *(const u16x8*)&smem[row * 144 + cb];
  }
}

// ---------- per-row exact candidate extraction (histogram select, prefix property) ----------

__global__ __launch_bounds__(256) void topk_kernel(const _Float16* __restrict__ d2,
                                                   u64* __restrict__ candR,
                                                   u32* __restrict__ candCnt) {
  __shared__ u16 rowbuf[NP];
  __shared__ u32 hist[NBINS];
  __shared__ u32 scanw[4];
  __shared__ int swred[4];
  __shared__ int sB;
  __shared__ u32 sCnt;
  const int i = blockIdx.x;
  const int t = threadIdx.x;
  const u16* row = (const u16*)(d2 + (size_t)i * NP);
  for (int b = t; b < NBINS; b += 256) hist[b] = 0;
  if (t == 0) sCnt = 0;
  __syncthreads();
  for (int base = t * 8; base < NP; base += 2048) {
    u16x8 v = *(const u16x8*)(row + base);
    *(u16x8*)&rowbuf[base] = v;
#pragma unroll
    for (int q = 0; q < 8; ++q) atomicAdd(&hist[v[q] >> 5], 1u);
  }
  __syncthreads();
  u32 loc[8]; u32 s = 0;
#pragma unroll
  for (int q = 0; q < 8; ++q) { loc[q] = hist[t * 8 + q]; s += loc[q]; }
  u32 pre = s;
  for (int off = 1; off < 64; off <<= 1) {
    u32 o = __shfl_up(pre, off);
    if ((t & 63) >= off) pre += o;
  }
  if ((t & 63) == 63) scanw[t >> 6] = pre;
  __syncthreads();
  u32 wbase = 0;
  for (int w = 0; w < (t >> 6); ++w) wbase += scanw[w];
  u32 c = wbase + pre - s;
  int lb = -1;
#pragma unroll
  for (int q = 0; q < 8; ++q) {
    c += loc[q];
    if (c >= 1 && c <= CAND_K) lb = t * 8 + q;
  }
#pragma unroll
  for (int off = 32; off >= 1; off >>= 1) {
    int o = __shfl_down(lb, off);
    lb = lb > o ? lb : o;
  }
  if ((t & 63) == 0) swred[t >> 6] = lb;
  __syncthreads();
  if (t == 0) {
    int m = swred[0];
#pragma unroll
    for (int w = 1; w < 4; ++w) m = m > swred[w] ? m : swred[w];
    sB = m;
  }
  __syncthreads();
  const int B = sB;
  if (B >= 0) {
    for (int base = t * 8; base < NP; base += 2048) {
#pragma unroll
      for (int q = 0; q < 8; ++q) {
        u16 v = rowbuf[base + q];
        if ((int)(v >> 5) <= B) {
          u32 pos = atomicAdd(&sCnt, 1u);
          if (pos < CAND_K) candR[(size_t)i * CAND_PAD + pos] = mkkey(v, i, base + q);
        }
      }
    }
  }
  __syncthreads();
  if (t == 0) {
    u32 n = sCnt;
    candCnt[i] = (n == 0 || n > CAND_K) ? 0x80000000u : n;
  }
}

// ---------- phase-1 per-round: WAVE-per-row cand scan; exhausted rows -> fallback list ----------

__global__ __launch_bounds__(256) void cand_min_kernel(
    const u64* __restrict__ candR, const u32* __restrict__ candCnt,
    const int* __restrict__ comp, u64* __restrict__ compmin,
    const int* __restrict__ nComps, int* __restrict__ fbList,
    int* __restrict__ fbCnt, int r) {
  if (*nComps == 1) return;
  const int t = threadIdx.x;
  const int lane = t & 63;
  const int i = blockIdx.x * 4 + (t >> 6);
  const int ci = comp[i];
  const u32 cc = candCnt[i];
  const int n = (int)(cc & 0x7fffffffu);
  u64 best = ~0ull;
  if (lane < n) {
    u64 key = candR[(size_t)i * CAND_PAD + lane];
    int lo = (int)((key >> 13) & 0x1FFF);
    int hi = (int)(key & 0x1FFF);
    int j = (lo == i) ? hi : lo;
    if (comp[j] != ci) best = key;
  }
#pragma unroll
  for (int off = 32; off >= 1; off >>= 1) {
    u64 o = __shfl_xor(best, off);
    best = best < o ? best : o;
  }
  if (lane == 0) {
    if (best != ~0ull) {  // flagged rows have n==0 -> best==~0 -> fallback
      atomicMin(&compmin[ci], best);
    } else {
      int p = atomicAdd(&fbCnt[r], 1);
      fbList[p] = i;
    }
  }
}

// ---------- phase-1 fallback: parallel block-per-row full scans over list ----------

__global__ __launch_bounds__(256) void fb_kernel(
    const _Float16* __restrict__ d2, const int* __restrict__ comp,
    u64* __restrict__ compmin, const int* __restrict__ fbList,
    const int* __restrict__ fbCnt, int r, const int* __restrict__ nComps) {
  if (*nComps == 1) return;
  __shared__ u64 sred[4];
  const int t = threadIdx.x;
  const int n = fbCnt[r];
  for (int idx = blockIdx.x; idx < n; idx += gridDim.x) {
    const int i = fbList[idx];
    const int ci = comp[i];
    const u16* row = (const u16*)(d2 + (size_t)i * NP);
    u64 best = ~0ull;
    for (int base = t * 8; base < NP; base += 2048) {
      u16x8 v = *(const u16x8*)(row + base);
      int4 c0 = *(const int4*)(comp + base);
      int4 c1 = *(const int4*)(comp + base + 4);
      int cs[8] = {c0.x, c0.y, c0.z, c0.w, c1.x, c1.y, c1.z, c1.w};
#pragma unroll
      for (int q = 0; q < 8; ++q) {
        if (cs[q] != ci) {
          u64 k = mkkey(v[q], i, base + q);
          best = k < best ? k : best;
        }
      }
    }
#pragma unroll
    for (int off = 32; off >= 1; off >>= 1) {
      u64 o = __shfl_down(best, off);
      best = best < o ? best : o;
    }
    if ((t & 63) == 0) sred[t >> 6] = best;
    __syncthreads();
    if (t == 0) {
      best = sred[0];
#pragma unroll
      for (int w = 1; w < 4; ++w) best = best < sred[w] ? best : sred[w];
      if (best != ~0ull) atomicMin(&compmin[ci], best);
    }
    __syncthreads();
  }
}

// ---------- phase-1 select (structural 2-cycle dedupe), exact fp32 weights ----------

__global__ void select_kernel(const float* __restrict__ X, const float* __restrict__ sq,
                              const int* __restrict__ comp, const u64* __restrict__ compmin,
                              int* __restrict__ parent, float* __restrict__ edgeW,
                              int* __restrict__ edgeCnt, const int* __restrict__ nComps) {
  int c = blockIdx.x * blockDim.x + threadIdx.x;
  if (c >= NP) return;
  if (*nComps == 1) { parent[c] = c; return; }
  u64 m = compmin[c];
  if (m == ~0ull) { parent[c] = c; return; }
  int a = (int)((m >> 13) & 0x1FFF);
  int b = (int)(m & 0x1FFF);
  int j = (comp[a] == c) ? b : a;
  int d = comp[j];
  bool mutual = false;
  u64 md = compmin[d];
  if (md != ~0ull) {
    int a2 = (int)((md >> 13) & 0x1FFF);
    int b2 = (int)(md & 0x1FFF);
    int j2 = (comp[a2] == d) ? b2 : a2;
    mutual = (comp[j2] == c);
  }
  if (mutual && c > d) { parent[c] = d; return; }
  parent[c] = mutual ? c : d;
  const float4* pa = (const float4*)(X + (size_t)a * DF);
  const float4* pb = (const float4*)(X + (size_t)b * DF);
  float dot = 0.f;
#pragma unroll 8
  for (int k = 0; k < DF / 4; ++k) {
    float4 va = pa[k], vb = pb[k];
    dot += va.x * vb.x + va.y * vb.y + va.z * vb.z + va.w * vb.w;
  }
  float dd = sq[a] + sq[b] - 2.f * dot;
  float w = sqrtf(fmaxf(dd, 0.f) + 1e-12f);
  int idx = atomicAdd(edgeCnt, 1);
  if (idx < NP) edgeW[idx] = w;
}

// ---------- phase-1 pointer-jump + relabel + count; DENSE also builds contraction maps ----------

template <bool DENSE>
__global__ __launch_bounds__(1024) void jump_relabel_kernel(
    const int* __restrict__ parent, int* __restrict__ comp,
    u64* __restrict__ compmin, int* __restrict__ nComps,
    u16* __restrict__ dcomp, int* __restrict__ comp2,
    u64* __restrict__ compmin2, int* __restrict__ ncDense) {
  if (*nComps == 1) return;
  __shared__ int sp[NP];
  __shared__ u16 did[NP];
  __shared__ int swsum[16];
  __shared__ int scnt;
  __shared__ int sch;
  const int t = threadIdx.x;
  const int lane = t & 63, wv = t >> 6;
  for (int c = t; c < NP; c += 1024) { sp[c] = parent[c]; did[c] = 0; }
  if (t == 0) { scnt = 0; sch = 0; }
  __syncthreads();
  for (int it = 0; it < 13; ++it) {
    int ch = 0;
    for (int c = t; c < NP; c += 1024) {
      int p = sp[c];
      int pp = sp[p];
      if (p != pp) { sp[c] = pp; ch = 1; }
    }
    if (ch) sch = 1;
    __syncthreads();
    if (!sch) break;
    __syncthreads();
    if (t == 0) sch = 0;
    __syncthreads();
  }
  for (int i = t; i < NP; i += 1024) {
    int nc = sp[comp[i]];
    comp[i] = nc;
    did[nc] = 1;
  }
  __syncthreads();
  if constexpr (!DENSE) {
    int part = 0;
    for (int c = t; c < NP; c += 1024) part += did[c];
#pragma unroll
    for (int off = 32; off >= 1; off >>= 1) part += __shfl_down(part, off);
    if (lane == 0) atomicAdd(&scnt, part);
    for (int c = t; c < NP; c += 1024) compmin[c] = ~0ull;
    __syncthreads();
    if (t == 0) *nComps = scnt;
  } else {
    // dense ids via block prefix sum over 8192 flags (8 per thread)
    int f[8]; int s = 0;
#pragma unroll
    for (int q = 0; q < 8; ++q) { f[q] = did[t * 8 + q]; s += f[q]; }
    int incl = s;
    for (int off = 1; off < 64; off <<= 1) {
      int o = __shfl_up(incl, off);
      if (lane >= off) incl += o;
    }
    if (lane == 63) swsum[wv] = incl;
    __syncthreads();
    int wbase = 0;
    for (int w = 0; w < wv; ++w) wbase += swsum[w];
    int e = wbase + incl - s;
#pragma unroll
    for (int q = 0; q < 8; ++q) {
      if (f[q]) { did[t * 8 + q] = (u16)e; ++e; }
    }
    __syncthreads();
    for (int i = t; i < NP; i += 1024) dcomp[i] = did[comp[i]];
    if (t < NC) { comp2[t] = t; compmin2[t] = ~0ull; }
    if (t == 0) {
      int total = 0;
#pragma unroll
      for (int w = 0; w < 16; ++w) total += swsum[w];
      *nComps = total;
      *ncDense = total;
    }
  }
}

// ---------- M init (all-ones) ----------

__global__ __launch_bounds__(256) void minit_kernel(u64* __restrict__ M) {
  int idx = (blockIdx.x * 256 + threadIdx.x) * 4;
#pragma unroll
  for (int q = 0; q < 4; ++q) M[idx + q] = ~0ull;
}

// ---------- contract: full d2 pass -> M[NC][NC] exact min keys ----------

__global__ __launch_bounds__(256) void contract_kernel(
    const _Float16* __restrict__ d2, const u16* __restrict__ dcomp,
    u64* __restrict__ M) {
  __shared__ u32 table[NC];
  const int i = blockIdx.x;
  const int t = threadIdx.x;
  for (int b = t; b < NC; b += 256) table[b] = ~0u;
  __syncthreads();
  const int ci = dcomp[i];
  const u16* row = (const u16*)(d2 + (size_t)i * NP);
  for (int base = t * 8; base < NP; base += 2048) {
    u16x8 v = *(const u16x8*)(row + base);
    u16x8 cj = *(const u16x8*)(dcomp + base);
#pragma unroll
    for (int q = 0; q < 8; ++q) {
      if (cj[q] != ci) {
        u32 k32 = ((u32)v[q] << 13) | (u32)(base + q);
        atomicMin(&table[cj[q]], k32);
      }
    }
  }
  __syncthreads();
  for (int b = t; b < NC; b += 256) {
    u32 k32 = table[b];
    if (k32 != ~0u) {
      u64 key = mkkey(k32 >> 13, i, (int)(k32 & 0x1FFF));
      u64* addr = &M[(size_t)ci * NC + b];
      if (key < *addr) atomicMin(addr, key);  // stale-read filter safe: M only decreases
    }
  }
}

// ---------- phase-2: row min over M ----------

__global__ __launch_bounds__(64) void rmin2_kernel(const u64* __restrict__ M,
                                                   const int* __restrict__ comp2,
                                                   u64* __restrict__ compmin2,
                                                   const int* __restrict__ nComps) {
  if (*nComps == 1) return;
  const int a = blockIdx.x;
  const int t = threadIdx.x;
  const int ca = comp2[a];
  u64 best = ~0ull;
  for (int b = t; b < NC; b += 64) {
    u64 k = M[(size_t)a * NC + b];
    if (k != ~0ull && comp2[b] != ca && k < best) best = k;
  }
#pragma unroll
  for (int off = 32; off >= 1; off >>= 1) {
    u64 o = __shfl_down(best, off);
    best = best < o ? best : o;
  }
  if (t == 0 && best != ~0ull) atomicMin(&compmin2[ca], best);
}

// ---------- phase-2 FUSED select + jump + relabel + count (single block, NC threads) ----------

__global__ __launch_bounds__(NC) void sel_jump2_kernel(
    const float* __restrict__ X, const float* __restrict__ sq,
    const u16* __restrict__ dcomp, int* __restrict__ comp2,
    u64* __restrict__ compmin2, float* __restrict__ edgeW,
    int* __restrict__ edgeCnt, int* __restrict__ nComps,
    const int* __restrict__ ncDense) {
  if (*nComps == 1) return;
  __shared__ int sp[NC];
  __shared__ u16 fl[NC];
  __shared__ int scnt;
  const int t = threadIdx.x;  // role: component id c
  // --- select (reads comp2/compmin2 written by previous kernels) ---
  int par = t;
  bool doEdge = false;
  int ea = 0, eb = 0;
  u64 m = compmin2[t];
  if (m != ~0ull) {
    int a = (int)((m >> 13) & 0x1FFF);
    int b = (int)(m & 0x1FFF);
    int j = (comp2[dcomp[a]] == t) ? b : a;
    int d = comp2[dcomp[j]];
    bool mutual = false;
    u64 md = compmin2[d];
    if (md != ~0ull) {
      int a2 = (int)((md >> 13) & 0x1FFF);
      int b2 = (int)(md & 0x1FFF);
      int j2 = (comp2[dcomp[a2]] == d) ? b2 : a2;
      mutual = (comp2[dcomp[j2]] == t);
    }
    if (mutual && t > d) {
      par = d;
    } else {
      par = mutual ? t : d;
      doEdge = true; ea = a; eb = b;
    }
  }
  sp[t] = par;
  fl[t] = 0;
  if (t == 0) scnt = 0;
  if (doEdge) {
    const float4* pa = (const float4*)(X + (size_t)ea * DF);
    const float4* pb = (const float4*)(X + (size_t)eb * DF);
    float dot = 0.f;
#pragma unroll 8
    for (int k = 0; k < DF / 4; ++k) {
      float4 va = pa[k], vb = pb[k];
      dot += va.x * vb.x + va.y * vb.y + va.z * vb.z + va.w * vb.w;
    }
    float dd = sq[ea] + sq[eb] - 2.f * dot;
    float w = sqrtf(fmaxf(dd, 0.f) + 1e-12f);
    int idx = atomicAdd(edgeCnt, 1);
    if (idx < NP) edgeW[idx] = w;
  }
  __syncthreads();
  // --- pointer jump ---
#pragma unroll
  for (int it = 0; it < 9; ++it) {
    sp[t] = sp[sp[t]];
    __syncthreads();
  }
  int nd = *ncDense;
  int nc2 = sp[comp2[t]];
  comp2[t] = nc2;
  if (t < nd) fl[nc2] = 1;
  __syncthreads();
  int part = fl[t];
#pragma unroll
  for (int off = 32; off >= 1; off >>= 1) part += __shfl_down(part, off);
  if ((t & 63) == 0) atomicAdd(&scnt, part);
  compmin2[t] = ~0ull;
  __syncthreads();
  if (t == 0) *nComps = scnt;
}

// ---------- entropy over edge weights ----------

__global__ __launch_bounds__(1024) void entropy_kernel(const float* __restrict__ edgeW,
                                                       const int* __restrict__ edgeCnt,
                                                       float* __restrict__ out) {
  __shared__ float sred[16];
  __shared__ float stot;
  int ne = *edgeCnt;
  if (ne > NP) ne = NP;
  float s = 0.f;
  for (int k = threadIdx.x; k < ne; k += 1024) s += edgeW[k];
#pragma unroll
  for (int off = 32; off >= 1; off >>= 1) s += __shfl_down(s, off);
  int lane = threadIdx.x & 63, wv = threadIdx.x >> 6;
  if (lane == 0) sred[wv] = s;
  __syncthreads();
  if (threadIdx.x == 0) {
    float tt = 0.f;
#pragma unroll
    for (int w = 0; w < 16; ++w) tt += sred[w];
    stot = tt;
  }
  __syncthreads();
  float total = stot;
  float acc = 0.f;
  for (int k = threadIdx.x; k < ne; k += 1024) {
    float p = edgeW[k] / (total + 1e-12f);
    acc += p * logf(p + 1e-12f);
  }
#pragma unroll
  for (int off = 32; off >= 1; off >>= 1) acc += __shfl_down(acc, off);
  if (lane == 0) sred[wv] = acc;
  __syncthreads();
  if (threadIdx.x == 0) {
    float tt = 0.f;
#pragma unroll
    for (int w = 0; w < 16; ++w) tt += sred[w];
    out[0] = tt;  // loss = -entropy = sum p*log(p+eps); WEIGHT = 1
  }
}

// ---------- host-side driver ----------

extern "C" void kernel_launch(void* const* d_in, const int* in_sizes, int n_in,
                              void* d_out, int out_size, void* d_ws, size_t ws_size,
                              hipStream_t stream) {
  const float* X = (const float*)d_in[0];
  float* out = (float*)d_out;
  char* ws = (char*)d_ws;

  const size_t nn = (size_t)NP * NP;
  size_t off = (nn * 2 + 255) & ~(size_t)255;  // fp16 d2
  _Float16* d2 = (_Float16*)ws;
  float* sq = (float*)(ws + off);      off += (size_t)NP * 4;
  int* comp = (int*)(ws + off);        off += (size_t)NP * 4;
  u64* compmin = (u64*)(ws + off);     off += (size_t)NP * 8;
  int* parent = (int*)(ws + off);      off += (size_t)NP * 4;
  float* edgeW = (float*)(ws + off);   off += (size_t)NP * 4;
  u32* candCnt = (u32*)(ws + off);     off += (size_t)NP * 4;
  int* fbList = (int*)(ws + off);      off += (size_t)NP * 4;
  u16* dcomp = (u16*)(ws + off);       off += (size_t)NP * 2;
  int* comp2 = (int*)(ws + off);       off += (size_t)NC * 4;
  u64* compmin2 = (u64*)(ws + off);    off += (size_t)NC * 8;
  int* edgeCnt = (int*)(ws + off);     off += 64;
  int* nComps = (int*)(ws + off);      off += 64;
  int* ncDense = (int*)(ws + off);     off += 64;
  int* fbCnt = (int*)(ws + off);       off += 64;
  off = (off + 255) & ~(size_t)255;
  // region R: Xb (4 MB, dead after build) | candR (4 MB, dead after phase 1) | M (2 MB)
  u16* Xb = (u16*)(ws + off);
  u64* candR = (u64*)(ws + off);
  u64* M = (u64*)(ws + off);
  const size_t regionR = (size_t)NP * CAND_PAD * 8;  // 4 MB (max of the three)
  const bool PRE = (ws_size >= off + regionR);
  const bool useM = (ws_size >= off + (size_t)NC * NC * 8);

  init_kernel<<<NP / 256, 256, 0, stream>>>(comp, compmin, edgeCnt, nComps, fbCnt);
  sq_kernel<<<NP, 64, 0, stream>>>(X, sq);
  if (PRE) {
    cvt_kernel<<<NP * DF / (256 * 8), 256, 0, stream>>>(X, Xb);
    build_dist_kernel<true><<<dim3(NP / 128, NP / 128), 256, 0, stream>>>(X, Xb, sq, d2);
  } else {
    build_dist_kernel<false><<<dim3(NP / 128, NP / 128), 256, 0, stream>>>(X, Xb, sq, d2);
  }
  topk_kernel<<<NP, 256, 0, stream>>>(d2, candR, candCnt);

  const int p1 = useM ? PH1 : ALLR;
  for (int r = 0; r < p1; ++r) {
    cand_min_kernel<<<NP / 4, 256, 0, stream>>>(candR, candCnt, comp, compmin, nComps,
                                                fbList, fbCnt, r);
    fb_kernel<<<128, 256, 0, stream>>>(d2, comp, compmin, fbList, fbCnt, r, nComps);
    select_kernel<<<NP / 256, 256, 0, stream>>>(X, sq, comp, compmin, parent, edgeW,
                                                edgeCnt, nComps);
    if (useM && r == p1 - 1) {
      jump_relabel_kernel<true><<<1, 1024, 0, stream>>>(parent, comp, compmin, nComps,
                                                        dcomp, comp2, compmin2, ncDense);
    } else {
      jump_relabel_kernel<false><<<1, 1024, 0, stream>>>(parent, comp, compmin, nComps,
                                                         dcomp, comp2, compmin2, ncDense);
    }
  }

  if (useM) {
    minit_kernel<<<NC * NC / (256 * 4), 256, 0, stream>>>(M);
    contract_kernel<<<NP, 256, 0, stream>>>(d2, dcomp, M);
    for (int r = 0; r < PH2; ++r) {
      rmin2_kernel<<<NC, 64, 0, stream>>>(M, comp2, compmin2, nComps);
      sel_jump2_kernel<<<1, NC, 0, stream>>>(X, sq, dcomp, comp2, compmin2,
                                             edgeW, edgeCnt, nComps, ncDense);
    }
  }

  entropy_kernel<<<1, 1024, 0, stream>>>(edgeW, edgeCnt, out);
}